// Round 2
// baseline (513.156 us; speedup 1.0000x reference)
//
#include <hip/hip_runtime.h>
#include <stdint.h>

typedef unsigned short u16;
typedef __bf16 bf16x8 __attribute__((ext_vector_type(8)));
typedef float f32x4 __attribute__((ext_vector_type(4)));
typedef unsigned short u16x8 __attribute__((ext_vector_type(8)));

#define B_BATCH 8
#define S_LEN   2048
#define D_DIM   1024
#define U_DIM   1024

__device__ __forceinline__ float bf2f(u16 h) {
    union { unsigned u; float f; } c; c.u = ((unsigned)h) << 16; return c.f;
}
__device__ __forceinline__ u16 f2bf(float f) {
    union { float f; unsigned u; } c; c.f = f;
    unsigned r = c.u + 0x7fffu + ((c.u >> 16) & 1u);
    return (u16)(r >> 16);
}

// async global->LDS, 16B per lane. LDS dest is wave-uniform base + lane*16;
// our chunk ids are lane-contiguous per wave so layout matches exactly.
__device__ __forceinline__ void cp16(u16* lds, const u16* g) {
    __builtin_amdgcn_global_load_lds((__attribute__((address_space(1))) void*)g,
                                     (__attribute__((address_space(3))) void*)lds,
                                     16, 0, 0);
}

#define BM 128
#define BN 128
#define BK 32

// C[m][n] = (sum_k A[m][k] * Bt[n][k]) * scale + bias[n]; bf16 in, fp32 acc.
// OUTF32 selects fp32 or bf16 output. 256 thr = 4 waves, wave = 64x64 via
// 4x4 of mfma_f32_16x16x32_bf16. LDS: row-major K-inner, 16B chunks.
template<int OUTF32>
__global__ __launch_bounds__(256, 2) void gemm_bt(
    const u16* __restrict__ A, int lda, long long sA,
    const u16* __restrict__ Bt, int ldb, long long sB,
    void* __restrict__ Cv, int ldc, long long sC,
    const float* __restrict__ bias, float scale, int K)
{
    __shared__ __align__(16) u16 As[BM * BK];
    __shared__ __align__(16) u16 Bs[BN * BK];

    const int z = blockIdx.z;
    A  += (long long)z * sA;
    Bt += (long long)z * sB;

    const int n0 = blockIdx.x * BN;
    const int m0 = blockIdx.y * BM;
    const int tid = threadIdx.x;
    const int lane = tid & 63;
    const int wm = ((tid >> 6) >> 1) * 64;   // wave quadrant row
    const int wn = ((tid >> 6) & 1) * 64;    // wave quadrant col

    // staging chunk ids (16B each): thread covers chunk tid and tid+256 per tile
    const int c0 = tid, c1 = tid + 256;
    const int r0 = c0 >> 2, q0 = c0 & 3;
    const int r1 = c1 >> 2, q1 = c1 & 3;

    const int lm = lane & 15;   // fragment row/col within 16
    const int lq = lane >> 4;   // k-quad

    f32x4 acc[4][4] = {};

    for (int k0 = 0; k0 < K; k0 += BK) {
        __syncthreads();
        cp16(As + c0 * 8, A + (long long)(m0 + r0) * lda + k0 + q0 * 8);
        cp16(As + c1 * 8, A + (long long)(m0 + r1) * lda + k0 + q1 * 8);
        cp16(Bs + c0 * 8, Bt + (long long)(n0 + r0) * ldb + k0 + q0 * 8);
        cp16(Bs + c1 * 8, Bt + (long long)(n0 + r1) * ldb + k0 + q1 * 8);
        __syncthreads();

        bf16x8 af[4], bfr[4];
        #pragma unroll
        for (int i = 0; i < 4; ++i)
            af[i] = *(const bf16x8*)(As + (wm + i * 16 + lm) * BK + lq * 8);
        #pragma unroll
        for (int j = 0; j < 4; ++j)
            bfr[j] = *(const bf16x8*)(Bs + (wn + j * 16 + lm) * BK + lq * 8);
        #pragma unroll
        for (int i = 0; i < 4; ++i)
            #pragma unroll
            for (int j = 0; j < 4; ++j)
                acc[i][j] = __builtin_amdgcn_mfma_f32_16x16x32_bf16(af[i], bfr[j], acc[i][j], 0, 0, 0);
    }

    // C/D layout (m89-verified): col = lane&15, row = (lane>>4)*4 + reg
    const int col = lane & 15;
    const int rb  = (lane >> 4) * 4;
    #pragma unroll
    for (int j = 0; j < 4; ++j) {
        const int n = n0 + wn + j * 16 + col;
        const float bv = bias ? bias[n] : 0.0f;
        #pragma unroll
        for (int i = 0; i < 4; ++i) {
            const long long mr = m0 + wm + i * 16 + rb;
            #pragma unroll
            for (int r = 0; r < 4; ++r) {
                const float val = acc[i][j][r] * scale + bv;
                if (OUTF32) {
                    float* C = (float*)Cv + (long long)z * sC;
                    C[(mr + r) * ldc + n] = val;
                } else {
                    u16* C = (u16*)Cv + (long long)z * sC;
                    C[(mr + r) * ldc + n] = f2bf(val);
                }
            }
        }
    }
}

// fp32 -> bf16 elementwise, vectorized x4
__global__ __launch_bounds__(256) void cvt_f32_bf16(
    const float4* __restrict__ src, ushort4* __restrict__ dst, int n4)
{
    int i = blockIdx.x * 256 + threadIdx.x;
    if (i < n4) {
        float4 v = src[i];
        ushort4 o;
        o.x = f2bf(v.x); o.y = f2bf(v.y); o.z = f2bf(v.z); o.w = f2bf(v.w);
        dst[i] = o;
    }
}

// fp32 src [rows][cols] -> bf16 dst [cols][rows]
__global__ __launch_bounds__(256) void transpose_cvt(
    const float* __restrict__ src, u16* __restrict__ dst, int rows, int cols)
{
    __shared__ u16 tile[32][33];
    const int c0 = blockIdx.x * 32, rr0 = blockIdx.y * 32;
    const int tx = threadIdx.x & 31, ty = threadIdx.x >> 5;
    #pragma unroll
    for (int i = 0; i < 32; i += 8)
        tile[ty + i][tx] = f2bf(src[(long long)(rr0 + ty + i) * cols + c0 + tx]);
    __syncthreads();
    #pragma unroll
    for (int i = 0; i < 32; i += 8)
        dst[(long long)(c0 + ty + i) * rows + rr0 + tx] = tile[tx][ty + i];
}

// bf16 src [rows][cols] -> bf16 dst [cols][rows], batched over z
__global__ __launch_bounds__(256) void transpose_bf16(
    const u16* __restrict__ src, u16* __restrict__ dst,
    int rows, int cols, long long ss, long long ds)
{
    __shared__ u16 tile[32][33];
    src += (long long)blockIdx.z * ss;
    dst += (long long)blockIdx.z * ds;
    const int c0 = blockIdx.x * 32, rr0 = blockIdx.y * 32;
    const int tx = threadIdx.x & 31, ty = threadIdx.x >> 5;
    #pragma unroll
    for (int i = 0; i < 32; i += 8)
        tile[ty + i][tx] = src[(long long)(rr0 + ty + i) * cols + c0 + tx];
    __syncthreads();
    #pragma unroll
    for (int i = 0; i < 32; i += 8)
        dst[(long long)(c0 + ty + i) * rows + rr0 + tx] = tile[tx][ty + i];
}

// one block per score row (b*S + i); row length S_LEN=2048 = 256 thr * 8
__global__ __launch_bounds__(256) void softmax_rows(
    u16* __restrict__ Sc, const int* __restrict__ mask)
{
    const int row = blockIdx.x;
    const int b = row >> 11;          // / 2048
    const int i = row & 2047;
    u16* prow = Sc + (size_t)row * S_LEN;
    const int* mrow = mask + (size_t)b * S_LEN;
    const int tid = threadIdx.x;
    const int mi = mrow[i];

    u16x8 v = *(const u16x8*)(prow + tid * 8);
    const int4* m4 = (const int4*)mrow;
    int4 ma = m4[tid * 2];
    int4 mb = m4[tid * 2 + 1];
    int mj[8] = { ma.x, ma.y, ma.z, ma.w, mb.x, mb.y, mb.z, mb.w };

    float s[8];
    float lm = -3.0e38f;
    #pragma unroll
    for (int e = 0; e < 8; ++e) {
        s[e] = bf2f(v[e]) + ((mi & mj[e]) ? 0.0f : -10000.0f);
        lm = fmaxf(lm, s[e]);
    }
    #pragma unroll
    for (int off = 32; off > 0; off >>= 1)
        lm = fmaxf(lm, __shfl_xor(lm, off, 64));

    __shared__ float redm[4], reds[4];
    const int wave = tid >> 6, lane = tid & 63;
    if (lane == 0) redm[wave] = lm;
    __syncthreads();
    const float mfull = fmaxf(fmaxf(redm[0], redm[1]), fmaxf(redm[2], redm[3]));

    float e8[8];
    float ls = 0.0f;
    #pragma unroll
    for (int e = 0; e < 8; ++e) { e8[e] = __expf(s[e] - mfull); ls += e8[e]; }
    #pragma unroll
    for (int off = 32; off > 0; off >>= 1)
        ls += __shfl_xor(ls, off, 64);
    if (lane == 0) reds[wave] = ls;
    __syncthreads();
    const float inv = 1.0f / (reds[0] + reds[1] + reds[2] + reds[3]);

    u16x8 o;
    #pragma unroll
    for (int e = 0; e < 8; ++e) o[e] = f2bf(e8[e] * inv);
    *(u16x8*)(prow + tid * 8) = o;
}

extern "C" void kernel_launch(void* const* d_in, const int* in_sizes, int n_in,
                              void* d_out, int out_size, void* d_ws, size_t ws_size,
                              hipStream_t stream)
{
    (void)in_sizes; (void)n_in; (void)out_size; (void)ws_size;
    const float* x    = (const float*)d_in[0];
    const int*   mask = (const int*)d_in[1];
    const float* Wq   = (const float*)d_in[2];
    const float* bq   = (const float*)d_in[3];
    const float* Wk   = (const float*)d_in[4];
    const float* bk   = (const float*)d_in[5];
    const float* Wv   = (const float*)d_in[6];
    const float* bv   = (const float*)d_in[7];

    const size_t DU  = (size_t)D_DIM * U_DIM;           // 1,048,576
    const size_t BSU = (size_t)B_BATCH * S_LEN * U_DIM; // 16,777,216
    const long long SU = (long long)S_LEN * U_DIM;      // 2,097,152
    const long long SS = (long long)S_LEN * S_LEN;      // 4,194,304

    // ws layout (u16 elems): Qb | Kb | VTb | WqT | WkT | WvT | Sc (aliases xb)
    u16* ws  = (u16*)d_ws;
    u16* Qb  = ws;
    u16* Kb  = Qb + BSU;
    u16* VTb = Kb + BSU;
    u16* WqT = VTb + BSU;
    u16* WkT = WqT + DU;
    u16* WvT = WkT + DU;
    u16* Sc  = WvT + DU;       // B*S*S u16 = 64 MiB
    u16* xb  = Sc;             // alias: xb dead before Sc is written
    u16* Vst = (u16*)d_out;    // V staged as bf16 in d_out (overwritten by PV)

    dim3 blk(256);

    // 0) x fp32 -> bf16
    cvt_f32_bf16<<<dim3((unsigned)(BSU / 4 / 256)), blk, 0, stream>>>(
        (const float4*)x, (ushort4*)xb, (int)(BSU / 4));

    // 1) W^T fp32 [D][U] -> bf16 [U][D]
    transpose_cvt<<<dim3(32, 32, 1), blk, 0, stream>>>(Wq, WqT, D_DIM, U_DIM);
    transpose_cvt<<<dim3(32, 32, 1), blk, 0, stream>>>(Wk, WkT, D_DIM, U_DIM);
    transpose_cvt<<<dim3(32, 32, 1), blk, 0, stream>>>(Wv, WvT, D_DIM, U_DIM);

    // 2) Q/K/V projections: [16384 x 1024] @ W^T + bias -> bf16
    dim3 gproj(U_DIM / BN, (B_BATCH * S_LEN) / BM, 1);
    gemm_bt<0><<<gproj, blk, 0, stream>>>(xb, D_DIM, 0, WqT, D_DIM, 0, Qb,  U_DIM, 0, bq, 1.0f, D_DIM);
    gemm_bt<0><<<gproj, blk, 0, stream>>>(xb, D_DIM, 0, WkT, D_DIM, 0, Kb,  U_DIM, 0, bk, 1.0f, D_DIM);
    gemm_bt<0><<<gproj, blk, 0, stream>>>(xb, D_DIM, 0, WvT, D_DIM, 0, Vst, U_DIM, 0, bv, 1.0f, D_DIM);

    // 3) V^T per batch: [S][U] -> [U][S]
    transpose_bf16<<<dim3(U_DIM / 32, S_LEN / 32, B_BATCH), blk, 0, stream>>>(
        Vst, VTb, S_LEN, U_DIM, SU, SU);

    // 4) scores = Q K^T / 32 per batch -> Sc bf16 (xb is dead now)
    gemm_bt<0><<<dim3(S_LEN / BN, S_LEN / BM, B_BATCH), blk, 0, stream>>>(
        Qb, U_DIM, SU, Kb, U_DIM, SU, Sc, S_LEN, SS, (const float*)nullptr, 0.03125f, U_DIM);

    // 5) masked softmax rows, in place (bf16)
    softmax_rows<<<dim3(B_BATCH * S_LEN), blk, 0, stream>>>(Sc, mask);

    // 6) out = P V per batch -> fp32 d_out (overwrites V stash; only VT/Sc read)
    gemm_bt<1><<<dim3(U_DIM / BN, S_LEN / BM, B_BATCH), blk, 0, stream>>>(
        Sc, S_LEN, SS, VTb, S_LEN, SU, d_out, U_DIM, SU, (const float*)nullptr, 1.0f, S_LEN);
}

// Round 3
// 455.776 us; speedup vs baseline: 1.1259x; 1.1259x over previous
//
#include <hip/hip_runtime.h>
#include <stdint.h>

typedef unsigned short u16;
typedef __bf16 bf16x8 __attribute__((ext_vector_type(8)));
typedef float f32x4 __attribute__((ext_vector_type(4)));
typedef unsigned short u16x8 __attribute__((ext_vector_type(8)));

#define B_BATCH 8
#define S_LEN   2048
#define D_DIM   1024
#define U_DIM   1024

__device__ __forceinline__ float bf2f(u16 h) {
    union { unsigned u; float f; } c; c.u = ((unsigned)h) << 16; return c.f;
}
__device__ __forceinline__ u16 f2bf(float f) {
    union { float f; unsigned u; } c; c.f = f;
    unsigned r = c.u + 0x7fffu + ((c.u >> 16) & 1u);
    return (u16)(r >> 16);
}

__device__ __forceinline__ void cp16(u16* lds, const u16* g) {
    __builtin_amdgcn_global_load_lds((__attribute__((address_space(1))) void*)g,
                                     (__attribute__((address_space(3))) void*)lds,
                                     16, 0, 0);
}

#define BM 128
#define BN 128
#define BK 64   // 32 KB LDS/block -> 2 blocks/CU; 32 MFMA/wave per barrier

// C[m][n] = (sum_k A[m][k]*Bt[n][k])*scale + bias[n]; bf16 in, fp32 acc.
// OUTF32: fp32 vs bf16 out. ph: 0 = linear blockIdx; else z-pin to XCD
// (z = lid&7) + within-batch m-panels of height ph, m fastest (L2 locality).
// LDS bank-conflict fix: K-quad position XOR-swizzled by row&7 so any 8
// consecutive lanes of a ds_read_b128 hit 8 distinct bank quads.
template<int OUTF32>
__global__ __launch_bounds__(256, 2) void gemm_bt(
    const u16* __restrict__ A, int lda, long long sA,
    const u16* __restrict__ Bt, int ldb, long long sB,
    void* __restrict__ Cv, int ldc, long long sC,
    const float* __restrict__ bias, float scale, int K, int ph)
{
    __shared__ __align__(16) u16 As[BM * BK];
    __shared__ __align__(16) u16 Bs[BN * BK];

    int mi, ni, z;
    if (ph == 0) {
        ni = blockIdx.x; mi = blockIdx.y; z = blockIdx.z;
    } else {
        const int lid = blockIdx.x + gridDim.x * (blockIdx.y + gridDim.y * blockIdx.z);
        z = lid & 7;                    // batch pinned to XCD (lid%8 round-robin)
        const int t = lid >> 3;
        const int ntn = gridDim.x;
        const int panel = t / (ph * ntn);
        const int r = t - panel * (ph * ntn);
        mi = panel * ph + (r % ph);     // m fastest within panel
        ni = r / ph;
    }

    A  += (long long)z * sA;
    Bt += (long long)z * sB;
    const int n0 = ni * BN;
    const int m0 = mi * BM;

    const int tid = threadIdx.x;
    const int lane = tid & 63;
    const int wm = ((tid >> 6) >> 1) * 64;
    const int wn = ((tid >> 6) & 1) * 64;
    const int lm = lane & 15;
    const int lq = lane >> 4;
    const int sw = lm & 7;              // == row&7 for all fragment rows

    f32x4 acc[4][4] = {};

    for (int k0 = 0; k0 < K; k0 += BK) {
        __syncthreads();
        #pragma unroll
        for (int s = 0; s < 4; ++s) {
            const int c = tid + 256 * s;          // chunk position 0..1023
            const int r = c >> 3;
            const int q = (c & 7) ^ ((c >> 3) & 7); // global quad stored here
            cp16(As + c * 8, A + (long long)(m0 + r) * lda + k0 + q * 8);
            cp16(Bs + c * 8, Bt + (long long)(n0 + r) * ldb + k0 + q * 8);
        }
        __syncthreads();

        #pragma unroll
        for (int ks = 0; ks < 2; ++ks) {
            const int kq = ks * 4 + lq;
            bf16x8 af[4], bfr[4];
            #pragma unroll
            for (int i = 0; i < 4; ++i) {
                const int row = wm + i * 16 + lm;
                af[i] = *(const bf16x8*)(As + row * BK + (kq ^ sw) * 8);
            }
            #pragma unroll
            for (int j = 0; j < 4; ++j) {
                const int row = wn + j * 16 + lm;
                bfr[j] = *(const bf16x8*)(Bs + row * BK + (kq ^ sw) * 8);
            }
            #pragma unroll
            for (int i = 0; i < 4; ++i)
                #pragma unroll
                for (int j = 0; j < 4; ++j)
                    acc[i][j] = __builtin_amdgcn_mfma_f32_16x16x32_bf16(af[i], bfr[j], acc[i][j], 0, 0, 0);
        }
    }

    // C/D layout (m89-verified): col = lane&15, row = (lane>>4)*4 + reg
    const int col = lane & 15;
    const int rb  = (lane >> 4) * 4;
    #pragma unroll
    for (int j = 0; j < 4; ++j) {
        const int n = n0 + wn + j * 16 + col;
        const float bv = bias ? bias[n] : 0.0f;
        #pragma unroll
        for (int i = 0; i < 4; ++i) {
            const long long mr = m0 + wm + i * 16 + rb;
            #pragma unroll
            for (int r = 0; r < 4; ++r) {
                const float val = acc[i][j][r] * scale + bv;
                if (OUTF32) {
                    float* C = (float*)Cv + (long long)z * sC;
                    C[(mr + r) * ldc + n] = val;
                } else {
                    u16* C = (u16*)Cv + (long long)z * sC;
                    C[(mr + r) * ldc + n] = f2bf(val);
                }
            }
        }
    }
}

// fp32 -> bf16 elementwise, vectorized x4
__global__ __launch_bounds__(256) void cvt_f32_bf16(
    const float4* __restrict__ src, ushort4* __restrict__ dst, int n4)
{
    int i = blockIdx.x * 256 + threadIdx.x;
    if (i < n4) {
        float4 v = src[i];
        ushort4 o;
        o.x = f2bf(v.x); o.y = f2bf(v.y); o.z = f2bf(v.z); o.w = f2bf(v.w);
        dst[i] = o;
    }
}

// fp32 src [rows][cols] -> bf16 dst [cols][rows]
__global__ __launch_bounds__(256) void transpose_cvt(
    const float* __restrict__ src, u16* __restrict__ dst, int rows, int cols)
{
    __shared__ u16 tile[32][33];
    const int c0 = blockIdx.x * 32, rr0 = blockIdx.y * 32;
    const int tx = threadIdx.x & 31, ty = threadIdx.x >> 5;
    #pragma unroll
    for (int i = 0; i < 32; i += 8)
        tile[ty + i][tx] = f2bf(src[(long long)(rr0 + ty + i) * cols + c0 + tx]);
    __syncthreads();
    #pragma unroll
    for (int i = 0; i < 32; i += 8)
        dst[(long long)(c0 + ty + i) * rows + rr0 + tx] = tile[tx][ty + i];
}

// bf16 src [rows][cols] -> bf16 dst [cols][rows], batched over z
__global__ __launch_bounds__(256) void transpose_bf16(
    const u16* __restrict__ src, u16* __restrict__ dst,
    int rows, int cols, long long ss, long long ds)
{
    __shared__ u16 tile[32][33];
    src += (long long)blockIdx.z * ss;
    dst += (long long)blockIdx.z * ds;
    const int c0 = blockIdx.x * 32, rr0 = blockIdx.y * 32;
    const int tx = threadIdx.x & 31, ty = threadIdx.x >> 5;
    #pragma unroll
    for (int i = 0; i < 32; i += 8)
        tile[ty + i][tx] = src[(long long)(rr0 + ty + i) * cols + c0 + tx];
    __syncthreads();
    #pragma unroll
    for (int i = 0; i < 32; i += 8)
        dst[(long long)(c0 + ty + i) * rows + rr0 + tx] = tile[tx][ty + i];
}

// one block per score row; row length S_LEN=2048 = 256 thr * 8
__global__ __launch_bounds__(256) void softmax_rows(
    u16* __restrict__ Sc, const int* __restrict__ mask)
{
    const int row = blockIdx.x;
    const int b = row >> 11;
    const int i = row & 2047;
    u16* prow = Sc + (size_t)row * S_LEN;
    const int* mrow = mask + (size_t)b * S_LEN;
    const int tid = threadIdx.x;
    const int mi = mrow[i];

    u16x8 v = *(const u16x8*)(prow + tid * 8);
    const int4* m4 = (const int4*)mrow;
    int4 ma = m4[tid * 2];
    int4 mb = m4[tid * 2 + 1];
    int mj[8] = { ma.x, ma.y, ma.z, ma.w, mb.x, mb.y, mb.z, mb.w };

    float s[8];
    float lmx = -3.0e38f;
    #pragma unroll
    for (int e = 0; e < 8; ++e) {
        s[e] = bf2f(v[e]) + ((mi & mj[e]) ? 0.0f : -10000.0f);
        lmx = fmaxf(lmx, s[e]);
    }
    #pragma unroll
    for (int off = 32; off > 0; off >>= 1)
        lmx = fmaxf(lmx, __shfl_xor(lmx, off, 64));

    __shared__ float redm[4], reds[4];
    const int wave = tid >> 6, lane = tid & 63;
    if (lane == 0) redm[wave] = lmx;
    __syncthreads();
    const float mfull = fmaxf(fmaxf(redm[0], redm[1]), fmaxf(redm[2], redm[3]));

    float e8[8];
    float ls = 0.0f;
    #pragma unroll
    for (int e = 0; e < 8; ++e) { e8[e] = __expf(s[e] - mfull); ls += e8[e]; }
    #pragma unroll
    for (int off = 32; off > 0; off >>= 1)
        ls += __shfl_xor(ls, off, 64);
    if (lane == 0) reds[wave] = ls;
    __syncthreads();
    const float inv = 1.0f / (reds[0] + reds[1] + reds[2] + reds[3]);

    u16x8 o;
    #pragma unroll
    for (int e = 0; e < 8; ++e) o[e] = f2bf(e8[e] * inv);
    *(u16x8*)(prow + tid * 8) = o;
}

extern "C" void kernel_launch(void* const* d_in, const int* in_sizes, int n_in,
                              void* d_out, int out_size, void* d_ws, size_t ws_size,
                              hipStream_t stream)
{
    (void)in_sizes; (void)n_in; (void)out_size; (void)ws_size;
    const float* x    = (const float*)d_in[0];
    const int*   mask = (const int*)d_in[1];
    const float* Wq   = (const float*)d_in[2];
    const float* bq   = (const float*)d_in[3];
    const float* Wk   = (const float*)d_in[4];
    const float* bk   = (const float*)d_in[5];
    const float* Wv   = (const float*)d_in[6];
    const float* bv   = (const float*)d_in[7];

    const size_t DU  = (size_t)D_DIM * U_DIM;
    const size_t BSU = (size_t)B_BATCH * S_LEN * U_DIM;
    const long long SU = (long long)S_LEN * U_DIM;
    const long long SS = (long long)S_LEN * S_LEN;

    u16* ws  = (u16*)d_ws;
    u16* Qb  = ws;
    u16* Kb  = Qb + BSU;
    u16* VTb = Kb + BSU;
    u16* WqT = VTb + BSU;
    u16* WkT = WqT + DU;
    u16* WvT = WkT + DU;
    u16* Sc  = WvT + DU;       // 64 MiB
    u16* xb  = Sc;             // alias: xb dead before Sc is written
    u16* Vst = (u16*)d_out;    // V staged in d_out (overwritten by PV)

    dim3 blk(256);

    cvt_f32_bf16<<<dim3((unsigned)(BSU / 4 / 256)), blk, 0, stream>>>(
        (const float4*)x, (ushort4*)xb, (int)(BSU / 4));

    transpose_cvt<<<dim3(32, 32, 1), blk, 0, stream>>>(Wq, WqT, D_DIM, U_DIM);
    transpose_cvt<<<dim3(32, 32, 1), blk, 0, stream>>>(Wk, WkT, D_DIM, U_DIM);
    transpose_cvt<<<dim3(32, 32, 1), blk, 0, stream>>>(Wv, WvT, D_DIM, U_DIM);

    // Q/K/V projections (linear order: W is tiny, x rows stream once)
    dim3 gproj(U_DIM / BN, (B_BATCH * S_LEN) / BM, 1);
    gemm_bt<0><<<gproj, blk, 0, stream>>>(xb, D_DIM, 0, WqT, D_DIM, 0, Qb,  U_DIM, 0, bq, 1.0f, D_DIM, 0);
    gemm_bt<0><<<gproj, blk, 0, stream>>>(xb, D_DIM, 0, WkT, D_DIM, 0, Kb,  U_DIM, 0, bk, 1.0f, D_DIM, 0);
    gemm_bt<0><<<gproj, blk, 0, stream>>>(xb, D_DIM, 0, WvT, D_DIM, 0, Vst, U_DIM, 0, bv, 1.0f, D_DIM, 0);

    transpose_bf16<<<dim3(U_DIM / 32, S_LEN / 32, B_BATCH), blk, 0, stream>>>(
        Vst, VTb, S_LEN, U_DIM, SU, SU);

    // scores = Q K^T / 32: z-pinned to XCD, m-panels of 8 (Q 2MB + K 2MB in L2)
    gemm_bt<0><<<dim3(S_LEN / BN, S_LEN / BM, B_BATCH), blk, 0, stream>>>(
        Qb, U_DIM, SU, Kb, U_DIM, SU, Sc, S_LEN, SS, (const float*)nullptr, 0.03125f, U_DIM, 8);

    softmax_rows<<<dim3(B_BATCH * S_LEN), blk, 0, stream>>>(Sc, mask);

    // out = P V: z-pinned, column-major (m fastest; VT panel resident in L2)
    gemm_bt<1><<<dim3(U_DIM / BN, S_LEN / BM, B_BATCH), blk, 0, stream>>>(
        Sc, S_LEN, SS, VTb, S_LEN, SU, d_out, U_DIM, SU, (const float*)nullptr, 1.0f, S_LEN, 16);
}

// Round 4
// 369.585 us; speedup vs baseline: 1.3885x; 1.2332x over previous
//
#include <hip/hip_runtime.h>
#include <stdint.h>

typedef unsigned short u16;
typedef __bf16 bf16x8 __attribute__((ext_vector_type(8)));
typedef float f32x4 __attribute__((ext_vector_type(4)));
typedef unsigned short u16x8 __attribute__((ext_vector_type(8)));
typedef unsigned short u16x4 __attribute__((ext_vector_type(4)));

#define B_BATCH 8
#define S_LEN   2048
#define D_DIM   1024
#define U_DIM   1024

#define BM 128
#define BN 128
#define BK 64

__device__ __forceinline__ float bf2f(u16 h) {
    union { unsigned u; float f; } c; c.u = ((unsigned)h) << 16; return c.f;
}
__device__ __forceinline__ u16 f2bf(float f) {
    union { float f; unsigned u; } c; c.f = f;
    unsigned r = c.u + 0x7fffu + ((c.u >> 16) & 1u);
    return (u16)(r >> 16);
}

__device__ __forceinline__ void cp16(u16* lds, const u16* g) {
    __builtin_amdgcn_global_load_lds((__attribute__((address_space(1))) void*)g,
                                     (__attribute__((address_space(3))) void*)lds,
                                     16, 0, 0);
}

// Shared 128x128xK K-loop: global_load_lds staging (16B), XOR bank swizzle,
// 4 waves x 4x4 mfma_f32_16x16x32_bf16, fp32 acc. As/Bs are BM*BK u16 each.
__device__ __forceinline__ void gemm_core(
    const u16* __restrict__ A, int lda,
    const u16* __restrict__ Bt, int ldb,
    int m0, int n0, int K,
    u16* As, u16* Bs, int tid, f32x4 acc[4][4])
{
    const int lane = tid & 63;
    const int wm = ((tid >> 6) >> 1) * 64;
    const int wn = ((tid >> 6) & 1) * 64;
    const int lm = lane & 15;
    const int lq = lane >> 4;
    const int sw = lm & 7;

    for (int k0 = 0; k0 < K; k0 += BK) {
        __syncthreads();
        #pragma unroll
        for (int s = 0; s < 4; ++s) {
            const int c = tid + 256 * s;
            const int r = c >> 3;
            const int q = (c & 7) ^ ((c >> 3) & 7);
            cp16(As + c * 8, A + (long long)(m0 + r) * lda + k0 + q * 8);
            cp16(Bs + c * 8, Bt + (long long)(n0 + r) * ldb + k0 + q * 8);
        }
        __syncthreads();

        #pragma unroll
        for (int ks = 0; ks < 2; ++ks) {
            const int kq = ks * 4 + lq;
            bf16x8 af[4], bfr[4];
            #pragma unroll
            for (int i = 0; i < 4; ++i)
                af[i] = *(const bf16x8*)(As + (wm + i * 16 + lm) * BK + (kq ^ sw) * 8);
            #pragma unroll
            for (int j = 0; j < 4; ++j)
                bfr[j] = *(const bf16x8*)(Bs + (wn + j * 16 + lm) * BK + (kq ^ sw) * 8);
            #pragma unroll
            for (int i = 0; i < 4; ++i)
                #pragma unroll
                for (int j = 0; j < 4; ++j)
                    acc[i][j] = __builtin_amdgcn_mfma_f32_16x16x32_bf16(af[i], bfr[j], acc[i][j], 0, 0, 0);
        }
    }
}

// z-pinned (z = lid&7 -> XCD) + m-panel swizzle for L2 locality
__device__ __forceinline__ void swizzle_mnz(int ph, int& mi, int& ni, int& z) {
    const int lid = blockIdx.x + gridDim.x * (blockIdx.y + gridDim.y * blockIdx.z);
    z = lid & 7;
    const int t = lid >> 3;
    const int ntn = gridDim.x;
    const int panel = t / (ph * ntn);
    const int r = t - panel * (ph * ntn);
    mi = panel * ph + (r % ph);
    ni = r / ph;
}

// ---------------- kernel 1: prep (x cvt, W transposes, rowsum zero) --------
__global__ __launch_bounds__(256) void prep(
    const float* __restrict__ x, u16* __restrict__ xb,
    const float* __restrict__ Wq, const float* __restrict__ Wk,
    const float* __restrict__ Wv, u16* __restrict__ WT,
    float* __restrict__ rowsum)
{
    __shared__ u16 tile[32][33];
    const int b = blockIdx.x;
    const int tid = threadIdx.x;
    if (b < 16384) {
        // x fp32 -> bf16, 1 float4 per thread, exact cover
        const int i = b * 256 + tid;
        float4 v = ((const float4*)x)[i];
        ushort4 o;
        o.x = f2bf(v.x); o.y = f2bf(v.y); o.z = f2bf(v.z); o.w = f2bf(v.w);
        ((ushort4*)xb)[i] = o;
    } else if (b < 16384 + 3072) {
        const int b2 = b - 16384;
        const int w = b2 >> 10;
        const int idx = b2 & 1023;
        const float* src = (w == 0) ? Wq : (w == 1) ? Wk : Wv;
        u16* dst = WT + (size_t)w * D_DIM * U_DIM;
        const int c0 = (idx & 31) * 32, rr0 = (idx >> 5) * 32;
        const int tx = tid & 31, ty = tid >> 5;
        #pragma unroll
        for (int i = 0; i < 32; i += 8)
            tile[ty + i][tx] = f2bf(src[(long long)(rr0 + ty + i) * U_DIM + c0 + tx]);
        __syncthreads();
        #pragma unroll
        for (int i = 0; i < 32; i += 8)
            dst[(long long)(c0 + ty + i) * D_DIM + rr0 + tx] = tile[tx][ty + i];
    } else {
        const int i = (b - 16384 - 3072) * 256 + tid;   // < 4096, exact
        float4 z4; z4.x = z4.y = z4.z = z4.w = 0.0f;
        ((float4*)rowsum)[i] = z4;
    }
}

// ------------- kernel 2: fused QKV projection (V written transposed) -------
// grid (24, 128): tgt = bx>>3 selects Q/K/V, ni = bx&7, mi = by.
__global__ __launch_bounds__(256, 2) void qkv_proj(
    const u16* __restrict__ xb, const u16* __restrict__ WT,
    const float* __restrict__ bq, const float* __restrict__ bk,
    const float* __restrict__ bv,
    u16* __restrict__ Q, u16* __restrict__ Ko, u16* __restrict__ VT)
{
    __shared__ __align__(16) u16 smem[BM * BK * 2];   // As|Bs, reused as T[128][128]
    u16* As = smem;
    u16* Bs = smem + BM * BK;

    const int tgt = blockIdx.x >> 3;
    const int n0 = (blockIdx.x & 7) * BN;
    const int m0 = blockIdx.y * BM;
    const int tid = threadIdx.x;
    const int lane = tid & 63;
    const int wm = ((tid >> 6) >> 1) * 64;
    const int wn = ((tid >> 6) & 1) * 64;

    const u16* Bt = WT + (size_t)tgt * (D_DIM * U_DIM);
    const float* bias = (tgt == 0) ? bq : (tgt == 1) ? bk : bv;

    f32x4 acc[4][4] = {};
    gemm_core(xb, D_DIM, Bt, D_DIM, m0, n0, D_DIM, As, Bs, tid, acc);

    const int col = lane & 15;
    const int rb  = (lane >> 4) * 4;

    if (tgt < 2) {
        u16* C = (tgt == 0) ? Q : Ko;
        #pragma unroll
        for (int j = 0; j < 4; ++j) {
            const int n = n0 + wn + j * 16 + col;
            const float bvv = bias[n];
            #pragma unroll
            for (int i = 0; i < 4; ++i) {
                const long long mr = m0 + wm + i * 16 + rb;
                #pragma unroll
                for (int r = 0; r < 4; ++r)
                    C[(mr + r) * U_DIM + n] = f2bf(acc[i][j][r] + bvv);
            }
        }
    } else {
        // V: transpose 128x128 tile through LDS, write VT[u][s] coalesced.
        // T element (row=m-local, col=n-local) at u16 idx:
        //   col*128 + ((row>>3)^(col&15))*8 + (row&7)   (XOR bank swizzle)
        __syncthreads();   // done with As/Bs K-loop reads
        #pragma unroll
        for (int j = 0; j < 4; ++j) {
            const int cl = wn + j * 16 + col;
            const float bvv = bias[n0 + cl];
            #pragma unroll
            for (int i = 0; i < 4; ++i) {
                const int rowb = wm + i * 16 + rb;     // rows rowb..rowb+3, same 8-block
                u16x4 pk;
                #pragma unroll
                for (int r = 0; r < 4; ++r) pk[r] = f2bf(acc[i][j][r] + bvv);
                const int idx = cl * 128 + (((rowb >> 3) ^ (cl & 15)) * 8) + (rowb & 7);
                *(u16x4*)(smem + idx) = pk;
            }
        }
        __syncthreads();
        const int zb = m0 >> 11;            // batch
        const int s0 = m0 & 2047;           // seq offset within batch
        u16* VTg = VT + (size_t)zb * ((size_t)S_LEN * U_DIM);
        #pragma unroll
        for (int s = 0; s < 8; ++s) {
            const int cid = tid + 256 * s;   // 2048 chunks: col(128) x m8(16)
            const int cl = cid >> 4;
            const int m8 = cid & 15;
            u16x8 v = *(const u16x8*)(smem + cl * 128 + ((m8 ^ (cl & 15)) * 8));
            *(u16x8*)(VTg + (size_t)(n0 + cl) * S_LEN + s0 + m8 * 8) = v;
        }
    }
}

// ------ kernel 3: scores + exp + mask + rowsum (softmax w/o max-sub) -------
__global__ __launch_bounds__(256, 2) void scores_exp(
    const u16* __restrict__ Qb, const u16* __restrict__ Kb,
    u16* __restrict__ E, const int* __restrict__ mask,
    float* __restrict__ rowsum, int ph)
{
    __shared__ __align__(16) u16 smem[BM * BK * 2];
    u16* As = smem;
    u16* Bs = smem + BM * BK;

    int mi, ni, z;
    swizzle_mnz(ph, mi, ni, z);
    const int m0 = mi * BM, n0 = ni * BN;
    const long long SU = (long long)S_LEN * U_DIM;
    const long long SS = (long long)S_LEN * S_LEN;

    const int tid = threadIdx.x;
    const int lane = tid & 63;
    const int wm = ((tid >> 6) >> 1) * 64;
    const int wn = ((tid >> 6) & 1) * 64;

    f32x4 acc[4][4] = {};
    gemm_core(Qb + (long long)z * SU, U_DIM, Kb + (long long)z * SU, U_DIM,
              m0, n0, U_DIM, As, Bs, tid, acc);

    u16* Eg = E + (long long)z * SS;
    const int* mrow = mask + (size_t)z * S_LEN;
    const int col = lane & 15;
    const int rb  = (lane >> 4) * 4;

    int mj[4];
    #pragma unroll
    for (int j = 0; j < 4; ++j) mj[j] = mrow[n0 + wn + j * 16 + col];

    #pragma unroll
    for (int i = 0; i < 4; ++i) {
        #pragma unroll
        for (int r = 0; r < 4; ++r) {
            const int row = m0 + wm + i * 16 + rb + r;
            const int mi_ = mrow[row];
            float partial = 0.0f;
            #pragma unroll
            for (int j = 0; j < 4; ++j) {
                // m_i=0 row: uniform -1e4 shift cancels in softmax -> bias 0.
                // m_i=1 & m_j=0: exactly 0 (ref: exp(-1e4-..) == 0 in fp32).
                float e = (mi_ && !mj[j]) ? 0.0f : __expf(acc[i][j][r] * 0.03125f);
                const u16 h = f2bf(e);
                Eg[(long long)row * S_LEN + n0 + wn + j * 16 + col] = h;
                partial += bf2f(h);   // sum what PV will actually read
            }
            partial += __shfl_xor(partial, 1, 64);
            partial += __shfl_xor(partial, 2, 64);
            partial += __shfl_xor(partial, 4, 64);
            partial += __shfl_xor(partial, 8, 64);
            if ((lane & 15) == 0)
                atomicAdd(&rowsum[(size_t)z * S_LEN + row], partial);
        }
    }
}

// --------------- kernel 4: out = (E @ V) / rowsum, fp32 out ----------------
__global__ __launch_bounds__(256, 2) void pv_gemm(
    const u16* __restrict__ E, const u16* __restrict__ VT,
    float* __restrict__ out, const float* __restrict__ rowsum, int ph)
{
    __shared__ __align__(16) u16 smem[BM * BK * 2];
    u16* As = smem;
    u16* Bs = smem + BM * BK;

    int mi, ni, z;
    swizzle_mnz(ph, mi, ni, z);
    const int m0 = mi * BM, n0 = ni * BN;
    const long long SU = (long long)S_LEN * U_DIM;
    const long long SS = (long long)S_LEN * S_LEN;

    const int tid = threadIdx.x;
    const int lane = tid & 63;
    const int wm = ((tid >> 6) >> 1) * 64;
    const int wn = ((tid >> 6) & 1) * 64;

    f32x4 acc[4][4] = {};
    gemm_core(E + (long long)z * SS, S_LEN, VT + (long long)z * SU, S_LEN,
              m0, n0, S_LEN, As, Bs, tid, acc);

    float* Cg = out + (long long)z * SU;
    const float* rs = rowsum + (size_t)z * S_LEN;
    const int col = lane & 15;
    const int rb  = (lane >> 4) * 4;

    #pragma unroll
    for (int i = 0; i < 4; ++i) {
        #pragma unroll
        for (int r = 0; r < 4; ++r) {
            const int row = m0 + wm + i * 16 + rb + r;
            const float inv = 1.0f / rs[row];
            #pragma unroll
            for (int j = 0; j < 4; ++j)
                Cg[(long long)row * U_DIM + n0 + wn + j * 16 + col] = acc[i][j][r] * inv;
        }
    }
}

extern "C" void kernel_launch(void* const* d_in, const int* in_sizes, int n_in,
                              void* d_out, int out_size, void* d_ws, size_t ws_size,
                              hipStream_t stream)
{
    (void)in_sizes; (void)n_in; (void)out_size; (void)ws_size;
    const float* x    = (const float*)d_in[0];
    const int*   mask = (const int*)d_in[1];
    const float* Wq   = (const float*)d_in[2];
    const float* bq   = (const float*)d_in[3];
    const float* Wk   = (const float*)d_in[4];
    const float* bk   = (const float*)d_in[5];
    const float* Wv   = (const float*)d_in[6];
    const float* bv   = (const float*)d_in[7];

    const size_t DU  = (size_t)D_DIM * U_DIM;
    const size_t BSU = (size_t)B_BATCH * S_LEN * U_DIM;

    // ws layout (u16 units): Qb | Kb | VTb | WT(x3) | rowsum | E (aliases xb)
    u16* ws  = (u16*)d_ws;
    u16* Qb  = ws;
    u16* Kb  = Qb + BSU;
    u16* VTb = Kb + BSU;
    u16* WT  = VTb + BSU;
    float* rowsum = (float*)(WT + 3 * DU);
    u16* E   = (u16*)(rowsum + (size_t)B_BATCH * S_LEN);
    u16* xb  = E;   // alias: xb dead before E is written

    dim3 blk(256);

    // 1) prep: x cvt (16384 blocks) + 3 W transposes (3072) + rowsum zero (16)
    prep<<<dim3(16384 + 3072 + 16), blk, 0, stream>>>(x, xb, Wq, Wk, Wv, WT, rowsum);

    // 2) fused QKV projections; V lands pre-transposed
    qkv_proj<<<dim3(24, 128), blk, 0, stream>>>(xb, WT, bq, bk, bv, Qb, Kb, VTb);

    // 3) E = exp(QK^T/32) masked, + rowsum atomics (z-pinned, m-panels of 8)
    scores_exp<<<dim3(S_LEN / BN, S_LEN / BM, B_BATCH), blk, 0, stream>>>(
        Qb, Kb, E, mask, rowsum, 8);

    // 4) out = (E V) / rowsum (z-pinned, m fastest for VT L2 residency)
    pv_gemm<<<dim3(U_DIM / BN, S_LEN / BM, B_BATCH), blk, 0, stream>>>(
        E, VTb, (float*)d_out, rowsum, 16);
}